// Round 4
// baseline (1532.903 us; speedup 1.0000x reference)
//
#include <hip/hip_runtime.h>
#include <cmath>

typedef __bf16 bf16;
typedef __bf16 bf16x8 __attribute__((ext_vector_type(8)));
typedef __bf16 bf16x4 __attribute__((ext_vector_type(4)));
typedef float f32x4 __attribute__((ext_vector_type(4)));
typedef unsigned int u32x4 __attribute__((ext_vector_type(4)));

#define LSEQ 2048
#define TOK 4096          // B*L
#define DMODEL 1024
#define DI 2048           // d_inner
#define DSTATE 16
#define DTR 64            // dt_rank
#define NX 96             // DTR + 2*DSTATE
#define KSPLIT 8

// ---------------- f32 -> bf16 convert (vector) ----------------
__global__ __launch_bounds__(256) void cvt_k(const float* __restrict__ src,
                                             bf16* __restrict__ dst, int n4) {
  const int i = blockIdx.x * 256 + threadIdx.x;
  if (i >= n4) return;
  const f32x4 v = ((const f32x4*)src)[i];
  bf16x4 o;
  o.x = (bf16)v.x; o.y = (bf16)v.y; o.z = (bf16)v.z; o.w = (bf16)v.w;
  ((bf16x4*)dst)[i] = o;
}

// ---------------- async global->LDS, width 16 ----------------
__device__ __forceinline__ void gld_lds16(const void* g, void* l) {
#if defined(__has_builtin) && __has_builtin(__builtin_amdgcn_global_load_lds)
  __builtin_amdgcn_global_load_lds(
      (const __attribute__((address_space(1))) unsigned int*)g,
      (__attribute__((address_space(3))) unsigned int*)l, 16, 0, 0);
#else
  *(u32x4*)l = *(const u32x4*)g;
#endif
}

// ---------------- NT GEMM: C[m,n] = sum_k A[m,k]*B[n,k] ----------------
// 128x128 tile, 256 threads (4 waves, 2x2 wave grid, each wave 4x4 of 16x16)
// MODE 0: store bf16 to outb[m*ldc+n]
// MODE 1: split-K partial f32 to outf[(bz*TOK+m)*NX+n], guard n<N
// MODE 2: bf16 softplus(acc + bias[n]) to outb[m*ldc+n]   (bias f32)
// MODE 3: store f32 to outf[m*ldc+n]
template <int MODE>
__global__ __launch_bounds__(256) void gemm_nt(
    const bf16* __restrict__ A, int lda, const bf16* __restrict__ Bm, int ldb,
    int N, int kLen, int ldc, bf16* __restrict__ outb,
    float* __restrict__ outf, const float* __restrict__ bias) {
  __shared__ alignas(16) bf16 sA[128 * 32];
  __shared__ alignas(16) bf16 sB[128 * 32];
  const int tid = threadIdx.x;
  const int wave = tid >> 6;
  const int lane = tid & 63;
  const int q = lane >> 4;
  const int r16 = lane & 15;
  const int m0 = blockIdx.y * 128;
  const int n0 = blockIdx.x * 128;
  const long k_start = (long)blockIdx.z * kLen;
  const int wm = (wave & 1) * 64;
  const int wn = (wave >> 1) * 64;

  f32x4 acc[4][4] = {};

  // staging: 512 chunks of 16B per tile buffer, 2 per thread.
  // LDS dest is wave-uniform base + lane*16; c*16 matches that order.
  const int c0 = tid, c1 = tid + 256;
  const int rA0 = c0 >> 2, kq0 = (c0 & 3) * 8;
  const int rA1 = c1 >> 2, kq1 = (c1 & 3) * 8;
  int rB0 = n0 + rA0; if (rB0 > N - 1) rB0 = N - 1;
  int rB1 = n0 + rA1; if (rB1 > N - 1) rB1 = N - 1;

  const bf16* gA0 = A + (long)(m0 + rA0) * lda + k_start + kq0;
  const bf16* gA1 = A + (long)(m0 + rA1) * lda + k_start + kq1;
  const bf16* gB0 = Bm + (long)rB0 * ldb + k_start + kq0;
  const bf16* gB1 = Bm + (long)rB1 * ldb + k_start + kq1;
  char* lA0 = (char*)sA + c0 * 16;
  char* lA1 = (char*)sA + c1 * 16;
  char* lB0 = (char*)sB + c0 * 16;
  char* lB1 = (char*)sB + c1 * 16;

  for (int k0 = 0; k0 < kLen; k0 += 32) {
    gld_lds16(gA0 + k0, lA0);
    gld_lds16(gA1 + k0, lA1);
    gld_lds16(gB0 + k0, lB0);
    gld_lds16(gB1 + k0, lB1);
    asm volatile("s_waitcnt vmcnt(0)" ::: "memory");
    __syncthreads();

    bf16x8 af[4], bg[4];
#pragma unroll
    for (int i = 0; i < 4; ++i)
      af[i] = *(const bf16x8*)(sA + (wm + i * 16 + r16) * 32 + q * 8);
#pragma unroll
    for (int j = 0; j < 4; ++j)
      bg[j] = *(const bf16x8*)(sB + (wn + j * 16 + r16) * 32 + q * 8);

#pragma unroll
    for (int i = 0; i < 4; ++i)
#pragma unroll
      for (int j = 0; j < 4; ++j)
        acc[i][j] = __builtin_amdgcn_mfma_f32_16x16x32_bf16(af[i], bg[j],
                                                            acc[i][j], 0, 0, 0);
    __syncthreads();
  }

#pragma unroll
  for (int i = 0; i < 4; ++i) {
#pragma unroll
    for (int j = 0; j < 4; ++j) {
#pragma unroll
      for (int r = 0; r < 4; ++r) {
        const int m = m0 + wm + i * 16 + q * 4 + r;
        const int n = n0 + wn + j * 16 + r16;
        const float v = acc[i][j][r];
        if (MODE == 0) {
          outb[(long)m * ldc + n] = (bf16)v;
        } else if (MODE == 1) {
          if (n < N) outf[((long)blockIdx.z * TOK + m) * NX + n] = v;
        } else if (MODE == 2) {
          const float xx = v + bias[n];
          const float sp = fmaxf(xx, 0.f) + log1pf(__expf(-fabsf(xx)));
          outb[(long)m * ldc + n] = (bf16)sp;
        } else {
          outf[(long)m * ldc + n] = v;
        }
      }
    }
  }
}

// ---------------- causal depthwise conv (k=4) + SiLU ----------------
// reads xc_raw bf16 [TOK, DI], f32 params; writes xcb bf16 [TOK, DI]
__global__ __launch_bounds__(256) void conv_silu_k(
    const bf16* __restrict__ xc_raw, const float* __restrict__ cw,
    const float* __restrict__ cb, bf16* __restrict__ xcb) {
  const int idx = blockIdx.x * 256 + threadIdx.x;  // tok*DI + d
  const int d = idx & (DI - 1);
  const int tok = idx >> 11;
  const int t = tok & (LSEQ - 1);
  float acc = cb[d];
#pragma unroll
  for (int j = 0; j < 4; ++j) {
    const int tt = t - 3 + j;
    if (tt >= 0)
      acc += cw[d * 4 + j] * (float)xc_raw[(long)(tok - 3 + j) * DI + d];
  }
  xcb[idx] = (bf16)(acc / (1.f + __expf(-acc)));
}

// ---------------- split-K reduce for x_dbl ----------------
__global__ __launch_bounds__(256) void xdbl_reduce_k(
    const float* __restrict__ part, float* __restrict__ xdbl,
    bf16* __restrict__ dtin) {
  const int idx = blockIdx.x * 256 + threadIdx.x;
  if (idx >= TOK * NX) return;
  float s = 0.f;
#pragma unroll
  for (int ks = 0; ks < KSPLIT; ++ks) s += part[(long)ks * TOK * NX + idx];
  xdbl[idx] = s;
  const int m = idx / NX;
  const int n = idx - m * NX;
  if (n < DTR) dtin[(long)m * DTR + n] = (bf16)s;
}

// ---------------- 16-lane reduction via DPP row_ror (VALU-speed) ----------
__device__ __forceinline__ float red16(float v) {
  int x;
  x = __builtin_amdgcn_update_dpp(0, __float_as_int(v), 0x128, 0xF, 0xF, true);
  v += __int_as_float(x);  // row_ror:8
  x = __builtin_amdgcn_update_dpp(0, __float_as_int(v), 0x124, 0xF, 0xF, true);
  v += __int_as_float(x);  // row_ror:4
  x = __builtin_amdgcn_update_dpp(0, __float_as_int(v), 0x122, 0xF, 0xF, true);
  v += __int_as_float(x);  // row_ror:2
  x = __builtin_amdgcn_update_dpp(0, __float_as_int(v), 0x121, 0xF, 0xF, true);
  v += __int_as_float(x);  // row_ror:1
  return v;
}

// ---------------- selective scan + gating epilogue ----------------
// 16 lanes per (b,d) pair (lane = state n); 16 pairs per 256-thread block.
// GRID: B_SZ*DI = 4096 pairs * 16 lanes / 256 = 256 blocks.
__global__ __launch_bounds__(256) void scan_k(
    const bf16* __restrict__ dtb, const bf16* __restrict__ xcb,
    const float* __restrict__ xdbl, const bf16* __restrict__ z,
    const float* __restrict__ A_log, const float* __restrict__ Dp,
    bf16* __restrict__ yg) {
  const int tid = threadIdx.x;
  const int n = tid & 15;
  const int p = blockIdx.x * 16 + (tid >> 4);  // p in [0, B_SZ*DI)
  const int b = p >> 11;                       // p / DI
  const int d = p & (DI - 1);
  const float A_dn = -__expf(A_log[d * DSTATE + n]);
  const float D_d = Dp[d];
  const long base = (long)b * LSEQ;

  constexpr int PF = 16;
  float dt_pf[PF], x_pf[PF], B_pf[PF], C_pf[PF];
  float z_pf[PF] = {};
#pragma unroll
  for (int i = 0; i < PF; ++i) {
    const long tok = base + i;
    dt_pf[i] = (float)dtb[tok * DI + d];
    x_pf[i] = (float)xcb[tok * DI + d];
    B_pf[i] = xdbl[tok * NX + DTR + n];
    C_pf[i] = xdbl[tok * NX + DTR + DSTATE + n];
    if (n == 0) z_pf[i] = (float)z[tok * DI + d];
  }
  float h = 0.f;
#pragma unroll 16
  for (int t = 0; t < LSEQ; ++t) {
    const int s = t & (PF - 1);
    const float dtv = dt_pf[s], xv = x_pf[s], Bv = B_pf[s], Cv = C_pf[s],
                zv = z_pf[s];
    const int tn = t + PF;
    if (tn < LSEQ) {
      const long tok = base + tn;
      dt_pf[s] = (float)dtb[tok * DI + d];
      x_pf[s] = (float)xcb[tok * DI + d];
      B_pf[s] = xdbl[tok * NX + DTR + n];
      C_pf[s] = xdbl[tok * NX + DTR + DSTATE + n];
      if (n == 0) z_pf[s] = (float)z[tok * DI + d];
    }
    const float dA = __expf(dtv * A_dn);
    h = dA * h + dtv * Bv * xv;
    const float y = red16(h * Cv);
    if (n == 0) {
      const float g = zv / (1.f + __expf(-zv));
      yg[(base + t) * DI + d] = (bf16)((y + D_d * xv) * g);
    }
  }
}

// ---------------- launcher ----------------
// ALL inputs/outputs are FLOAT32 (reference is pure f32; R2/R3 NaN came from
// reading f32 buffers as bf16 — odd elements are random mantissa bits, ~0.4%
// of which are bf16 NaN patterns). MFMA operands get explicit f32->bf16
// conversion into aliased workspace regions.
//
// Workspace (69.2 MB total, liveness-aliased):
//   z      16.78 MB bf16          (d2-d7)
//   xcb    16.78 MB bf16          (d3-d7)
//   regA   16.78 MB: xbf+wbf_in (c1-d2) | part f32 (d4-d5) | dt bf16 (d6-d7)
//                    | wbf_out (c5-d8)
//   regB   16.78 MB: xc_raw (d1-d3) | wbf_x,wbf_dt (c3-d6) | yg (d7-d8)
//   xdbl    1.57 MB f32           (d5-d7)
//   dtin    0.52 MB bf16          (d5-d6)
extern "C" void kernel_launch(void* const* d_in, const int* in_sizes, int n_in,
                              void* d_out, int out_size, void* d_ws,
                              size_t ws_size, hipStream_t stream) {
  const float* x = (const float*)d_in[0];        // [2,2048,1024]
  const float* in_proj = (const float*)d_in[1];  // [4096,1024]
  const float* conv_w = (const float*)d_in[2];   // [2048,1,4]
  const float* conv_b = (const float*)d_in[3];   // [2048]
  const float* A_log = (const float*)d_in[4];    // [2048,16]
  const float* Dp = (const float*)d_in[5];       // [2048]
  const float* x_proj = (const float*)d_in[6];   // [96,2048]
  const float* dt_proj = (const float*)d_in[7];  // [2048,64]
  const float* dt_b = (const float*)d_in[8];     // [2048]
  const float* out_proj = (const float*)d_in[9]; // [1024,2048]

  char* w = (char*)d_ws;
  bf16* z = (bf16*)w;       w += (long)TOK * DI * 2;
  bf16* xcb = (bf16*)w;     w += (long)TOK * DI * 2;
  char* regA = w;           w += (long)TOK * DI * 2;
  char* regB = w;           w += (long)TOK * DI * 2;
  float* xdbl = (float*)w;  w += (long)TOK * NX * 4;
  bf16* dtin = (bf16*)w;    w += (long)TOK * DTR * 2;

  bf16* xbf = (bf16*)regA;                        // 4.19M elems (c1-d2)
  bf16* wbf_in = (bf16*)regA + (long)TOK * DMODEL;// 4.19M elems (c2-d2)
  float* part = (float*)regA;                     // 12.58 MB (d4-d5)
  bf16* dt = (bf16*)regA;                         // 16.78 MB (d6-d7)
  bf16* wbf_out = (bf16*)regA;                    // 4.19 MB (c5-d8)
  bf16* xc_raw = (bf16*)regB;                     // (d1-d3)
  bf16* wbf_x = (bf16*)regB;                      // 196608 elems (c3-d4)
  bf16* wbf_dt = (bf16*)regB + 262144;            // 131072 elems (c4-d6)
  bf16* yg = (bf16*)regB;                         // (d7-d8)

  // c1/c2) convert x and in_proj to bf16
  cvt_k<<<4096, 256, 0, stream>>>(x, xbf, TOK * DMODEL / 4);
  cvt_k<<<4096, 256, 0, stream>>>(in_proj, wbf_in, 2 * DI * DMODEL / 4);
  // d1) xc_raw = x @ in_proj[0:2048]^T
  gemm_nt<0><<<dim3(16, 32, 1), 256, 0, stream>>>(
      xbf, DMODEL, wbf_in, DMODEL, DI, DMODEL, DI, xc_raw, nullptr, nullptr);
  // d2) z = x @ in_proj[2048:4096]^T
  gemm_nt<0><<<dim3(16, 32, 1), 256, 0, stream>>>(
      xbf, DMODEL, wbf_in + (long)DI * DMODEL, DMODEL, DI, DMODEL, DI, z,
      nullptr, nullptr);
  // d3) causal conv + SiLU -> xcb  (f32 params read directly)
  conv_silu_k<<<(TOK * DI) / 256, 256, 0, stream>>>(xc_raw, conv_w, conv_b,
                                                    xcb);
  // c3/c4) convert x_proj, dt_proj (regB free after d3)
  cvt_k<<<192, 256, 0, stream>>>(x_proj, wbf_x, NX * DI / 4);
  cvt_k<<<128, 256, 0, stream>>>(dt_proj, wbf_dt, DI * DTR / 4);
  // d4) x_dbl partials (split-K over K=2048)
  gemm_nt<1><<<dim3(1, 32, KSPLIT), 256, 0, stream>>>(
      xcb, DI, wbf_x, DI, NX, DI / KSPLIT, 0, nullptr, part, nullptr);
  // d5) reduce partials -> xdbl f32, dtin bf16
  xdbl_reduce_k<<<(TOK * NX) / 256, 256, 0, stream>>>(part, xdbl, dtin);
  // d6) dt = softplus(dtin @ dt_proj^T + dt_b)  bf16 [4096,2048]
  gemm_nt<2><<<dim3(16, 32, 1), 256, 0, stream>>>(
      dtin, DTR, wbf_dt, DTR, DI, DTR, DI, dt, nullptr, dt_b);
  // d7) selective scan + D-skip + silu(z) gate -> yg bf16
  scan_k<<<(2 * DI * DSTATE) / 256, 256, 0, stream>>>(dt, xcb, xdbl, z, A_log,
                                                      Dp, yg);
  // c5) convert out_proj (regA free after d7)
  cvt_k<<<2048, 256, 0, stream>>>(out_proj, wbf_out, DMODEL * DI / 4);
  // d8) out = yg @ out_proj^T -> f32 d_out
  gemm_nt<3><<<dim3(8, 32, 1), 256, 0, stream>>>(
      yg, DI, wbf_out, DI, DMODEL, DI, DMODEL, nullptr, (float*)d_out,
      nullptr);
}

// Round 5
// 389.503 us; speedup vs baseline: 3.9355x; 3.9355x over previous
//
#include <hip/hip_runtime.h>
#include <cmath>

typedef __bf16 bf16;
typedef __bf16 bf16x8 __attribute__((ext_vector_type(8)));
typedef __bf16 bf16x4 __attribute__((ext_vector_type(4)));
typedef float f32x4 __attribute__((ext_vector_type(4)));
typedef unsigned int u32x4 __attribute__((ext_vector_type(4)));

#define LSEQ 2048
#define TOK 4096          // B*L
#define DMODEL 1024
#define DI 2048           // d_inner
#define DSTATE 16
#define DTR 64            // dt_rank
#define NX 96             // DTR + 2*DSTATE
#define KSPLIT 8
#define NCH 32            // scan chunks
#define CH 64             // chunk length (NCH*CH == LSEQ)

// ---------------- f32 -> bf16 convert (vector) ----------------
__global__ __launch_bounds__(256) void cvt_k(const float* __restrict__ src,
                                             bf16* __restrict__ dst, int n4) {
  const int i = blockIdx.x * 256 + threadIdx.x;
  if (i >= n4) return;
  const f32x4 v = ((const f32x4*)src)[i];
  bf16x4 o;
  o.x = (bf16)v.x; o.y = (bf16)v.y; o.z = (bf16)v.z; o.w = (bf16)v.w;
  ((bf16x4*)dst)[i] = o;
}

// ---------------- async global->LDS, width 16 ----------------
__device__ __forceinline__ void gld_lds16(const void* g, void* l) {
#if defined(__has_builtin) && __has_builtin(__builtin_amdgcn_global_load_lds)
  __builtin_amdgcn_global_load_lds(
      (const __attribute__((address_space(1))) unsigned int*)g,
      (__attribute__((address_space(3))) unsigned int*)l, 16, 0, 0);
#else
  *(u32x4*)l = *(const u32x4*)g;
#endif
}

// ---------------- NT GEMM: C[m,n] = sum_k A[m,k]*B[n,k] ----------------
// MODE 0: bf16 out; MODE 1: split-K f32 partial (guard n<N);
// MODE 2: bf16 softplus(acc+bias); MODE 3: f32 out
template <int MODE>
__global__ __launch_bounds__(256) void gemm_nt(
    const bf16* __restrict__ A, int lda, const bf16* __restrict__ Bm, int ldb,
    int N, int kLen, int ldc, bf16* __restrict__ outb,
    float* __restrict__ outf, const float* __restrict__ bias) {
  __shared__ alignas(16) bf16 sA[128 * 32];
  __shared__ alignas(16) bf16 sB[128 * 32];
  const int tid = threadIdx.x;
  const int wave = tid >> 6;
  const int lane = tid & 63;
  const int q = lane >> 4;
  const int r16 = lane & 15;
  const int m0 = blockIdx.y * 128;
  const int n0 = blockIdx.x * 128;
  const long k_start = (long)blockIdx.z * kLen;
  const int wm = (wave & 1) * 64;
  const int wn = (wave >> 1) * 64;

  f32x4 acc[4][4] = {};

  const int c0 = tid, c1 = tid + 256;
  const int rA0 = c0 >> 2, kq0 = (c0 & 3) * 8;
  const int rA1 = c1 >> 2, kq1 = (c1 & 3) * 8;
  int rB0 = n0 + rA0; if (rB0 > N - 1) rB0 = N - 1;
  int rB1 = n0 + rA1; if (rB1 > N - 1) rB1 = N - 1;

  const bf16* gA0 = A + (long)(m0 + rA0) * lda + k_start + kq0;
  const bf16* gA1 = A + (long)(m0 + rA1) * lda + k_start + kq1;
  const bf16* gB0 = Bm + (long)rB0 * ldb + k_start + kq0;
  const bf16* gB1 = Bm + (long)rB1 * ldb + k_start + kq1;
  char* lA0 = (char*)sA + c0 * 16;
  char* lA1 = (char*)sA + c1 * 16;
  char* lB0 = (char*)sB + c0 * 16;
  char* lB1 = (char*)sB + c1 * 16;

  for (int k0 = 0; k0 < kLen; k0 += 32) {
    gld_lds16(gA0 + k0, lA0);
    gld_lds16(gA1 + k0, lA1);
    gld_lds16(gB0 + k0, lB0);
    gld_lds16(gB1 + k0, lB1);
    asm volatile("s_waitcnt vmcnt(0)" ::: "memory");
    __syncthreads();

    bf16x8 af[4], bg[4];
#pragma unroll
    for (int i = 0; i < 4; ++i)
      af[i] = *(const bf16x8*)(sA + (wm + i * 16 + r16) * 32 + q * 8);
#pragma unroll
    for (int j = 0; j < 4; ++j)
      bg[j] = *(const bf16x8*)(sB + (wn + j * 16 + r16) * 32 + q * 8);

#pragma unroll
    for (int i = 0; i < 4; ++i)
#pragma unroll
      for (int j = 0; j < 4; ++j)
        acc[i][j] = __builtin_amdgcn_mfma_f32_16x16x32_bf16(af[i], bg[j],
                                                            acc[i][j], 0, 0, 0);
    __syncthreads();
  }

#pragma unroll
  for (int i = 0; i < 4; ++i) {
#pragma unroll
    for (int j = 0; j < 4; ++j) {
#pragma unroll
      for (int r = 0; r < 4; ++r) {
        const int m = m0 + wm + i * 16 + q * 4 + r;
        const int n = n0 + wn + j * 16 + r16;
        const float v = acc[i][j][r];
        if (MODE == 0) {
          outb[(long)m * ldc + n] = (bf16)v;
        } else if (MODE == 1) {
          if (n < N) outf[((long)blockIdx.z * TOK + m) * NX + n] = v;
        } else if (MODE == 2) {
          const float xx = v + bias[n];
          const float sp = fmaxf(xx, 0.f) + log1pf(__expf(-fabsf(xx)));
          outb[(long)m * ldc + n] = (bf16)sp;
        } else {
          outf[(long)m * ldc + n] = v;
        }
      }
    }
  }
}

// ---------------- causal depthwise conv (k=4) + SiLU ----------------
__global__ __launch_bounds__(256) void conv_silu_k(
    const bf16* __restrict__ xc_raw, const float* __restrict__ cw,
    const float* __restrict__ cb, bf16* __restrict__ xcb) {
  const int idx = blockIdx.x * 256 + threadIdx.x;  // tok*DI + d
  const int d = idx & (DI - 1);
  const int tok = idx >> 11;
  const int t = tok & (LSEQ - 1);
  float acc = cb[d];
#pragma unroll
  for (int j = 0; j < 4; ++j) {
    const int tt = t - 3 + j;
    if (tt >= 0)
      acc += cw[d * 4 + j] * (float)xc_raw[(long)(tok - 3 + j) * DI + d];
  }
  xcb[idx] = (bf16)(acc / (1.f + __expf(-acc)));
}

// ---------------- split-K reduce for x_dbl ----------------
__global__ __launch_bounds__(256) void xdbl_reduce_k(
    const float* __restrict__ part, float* __restrict__ xdbl,
    bf16* __restrict__ dtin) {
  const int idx = blockIdx.x * 256 + threadIdx.x;
  if (idx >= TOK * NX) return;
  float s = 0.f;
#pragma unroll
  for (int ks = 0; ks < KSPLIT; ++ks) s += part[(long)ks * TOK * NX + idx];
  xdbl[idx] = s;
  const int m = idx / NX;
  const int n = idx - m * NX;
  if (n < DTR) dtin[(long)m * DTR + n] = (bf16)s;
}

// ============ chunked parallel selective scan ============
// One LANE per d; h[16] states in registers; dt/x/z loads coalesced over d;
// B/C loads wave-uniform (scalar-path). Grid: (DI/256, NCH, B_SZ).

// Pass 1: per chunk compute P_n = prod(a), S_n = local scan from h=0.
__global__ __launch_bounds__(256) void scan_p1(
    const bf16* __restrict__ dtb, const bf16* __restrict__ xcb,
    const float* __restrict__ xdbl, const float* __restrict__ A_log,
    float* __restrict__ PH, float* __restrict__ S) {
  const int d = blockIdx.x * 256 + threadIdx.x;
  const int c = blockIdx.y;
  const int b = blockIdx.z;
  const long base = (long)b * LSEQ + (long)c * CH;

  float A[DSTATE], h[DSTATE], P[DSTATE];
#pragma unroll
  for (int n = 0; n < DSTATE; ++n) {
    A[n] = -__expf(A_log[d * DSTATE + n]);
    h[n] = 0.f;
    P[n] = 1.f;
  }
  for (int t = 0; t < CH; ++t) {
    const long tok = base + t;
    const float dtv = (float)dtb[tok * DI + d];
    const float xv = (float)xcb[tok * DI + d];
    const float cm = dtv * xv;
    const float* bc = xdbl + tok * NX + DTR;  // wave-uniform
#pragma unroll
    for (int n = 0; n < DSTATE; ++n) {
      const float a = __expf(dtv * A[n]);
      h[n] = a * h[n] + cm * bc[n];
      P[n] *= a;
    }
  }
  const long idx = (((long)b * NCH + c) * DI + d) * DSTATE;
#pragma unroll
  for (int n = 0; n < DSTATE; ++n) {
    PH[idx + n] = P[n];
    S[idx + n] = h[n];
  }
}

// Combine: serial prefix over the NCH chunk summaries per (b,d,n).
// Writes incoming state Hin for each chunk IN PLACE over PH.
__global__ __launch_bounds__(256) void scan_comb(
    float* __restrict__ PH, const float* __restrict__ S) {
  const int q = blockIdx.x * 256 + threadIdx.x;  // [0, B*DI*DSTATE)
  const int n = q & (DSTATE - 1);
  const int dn = q >> 4;
  const int d = dn & (DI - 1);
  const int b = dn >> 11;
  float p[NCH], s[NCH];
#pragma unroll
  for (int c = 0; c < NCH; ++c) {
    const long idx = (((long)b * NCH + c) * DI + d) * DSTATE + n;
    p[c] = PH[idx];
    s[c] = S[idx];
  }
  float h = 0.f;
#pragma unroll
  for (int c = 0; c < NCH; ++c) {
    const long idx = (((long)b * NCH + c) * DI + d) * DSTATE + n;
    PH[idx] = h;            // incoming state for chunk c
    h = p[c] * h + s[c];
  }
}

// Pass 2: replay chunk from Hin, emit y = sum_n h_n*C_n, + D*x, * silu(z).
__global__ __launch_bounds__(256) void scan_p2(
    const bf16* __restrict__ dtb, const bf16* __restrict__ xcb,
    const float* __restrict__ xdbl, const bf16* __restrict__ z,
    const float* __restrict__ A_log, const float* __restrict__ Dp,
    const float* __restrict__ Hin, bf16* __restrict__ yg) {
  const int d = blockIdx.x * 256 + threadIdx.x;
  const int c = blockIdx.y;
  const int b = blockIdx.z;
  const long base = (long)b * LSEQ + (long)c * CH;
  const float D_d = Dp[d];

  float A[DSTATE], h[DSTATE];
  const long idx = (((long)b * NCH + c) * DI + d) * DSTATE;
#pragma unroll
  for (int n = 0; n < DSTATE; ++n) {
    A[n] = -__expf(A_log[d * DSTATE + n]);
    h[n] = Hin[idx + n];
  }
  for (int t = 0; t < CH; ++t) {
    const long tok = base + t;
    const float dtv = (float)dtb[tok * DI + d];
    const float xv = (float)xcb[tok * DI + d];
    const float zv = (float)z[tok * DI + d];
    const float cm = dtv * xv;
    const float* bc = xdbl + tok * NX + DTR;  // wave-uniform
    float y = 0.f;
#pragma unroll
    for (int n = 0; n < DSTATE; ++n) {
      const float a = __expf(dtv * A[n]);
      h[n] = a * h[n] + cm * bc[n];
      y += h[n] * bc[DSTATE + n];
    }
    const float g = zv / (1.f + __expf(-zv));
    yg[tok * DI + d] = (bf16)((y + D_d * xv) * g);
  }
}

// ---------------- launcher ----------------
// Workspace (86.0 MB, liveness-aliased):
//   z     16.78 MB bf16         (d2..s3)
//   xcb   16.78 MB bf16         (d3..s3)
//   regA  16.78 MB: xbf+wbf_in (c1-d2) | part (d4-d5) | dt bf16 (d6..s3)
//                   | wbf_out (c5-d8)
//   regB  16.78 MB: xc_raw (d1-d3) | wbf_x,wbf_dt (c3-d6) | yg (s3-d8)
//   xdbl   1.57 MB f32          (d5..s3)
//   dtin   0.52 MB bf16         (d5-d6)
//   PH     8.39 MB f32          (s1..s3; combine overwrites with Hin)
//   S      8.39 MB f32          (s1..s2)
extern "C" void kernel_launch(void* const* d_in, const int* in_sizes, int n_in,
                              void* d_out, int out_size, void* d_ws,
                              size_t ws_size, hipStream_t stream) {
  const float* x = (const float*)d_in[0];
  const float* in_proj = (const float*)d_in[1];
  const float* conv_w = (const float*)d_in[2];
  const float* conv_b = (const float*)d_in[3];
  const float* A_log = (const float*)d_in[4];
  const float* Dp = (const float*)d_in[5];
  const float* x_proj = (const float*)d_in[6];
  const float* dt_proj = (const float*)d_in[7];
  const float* dt_b = (const float*)d_in[8];
  const float* out_proj = (const float*)d_in[9];

  char* w = (char*)d_ws;
  bf16* z = (bf16*)w;       w += (long)TOK * DI * 2;
  bf16* xcb = (bf16*)w;     w += (long)TOK * DI * 2;
  char* regA = w;           w += (long)TOK * DI * 2;
  char* regB = w;           w += (long)TOK * DI * 2;
  float* xdbl = (float*)w;  w += (long)TOK * NX * 4;
  bf16* dtin = (bf16*)w;    w += (long)TOK * DTR * 2;
  float* PH = (float*)w;    w += (long)2 * NCH * DI * DSTATE * 4;
  float* S = (float*)w;     w += (long)2 * NCH * DI * DSTATE * 4;

  bf16* xbf = (bf16*)regA;
  bf16* wbf_in = (bf16*)regA + (long)TOK * DMODEL;
  float* part = (float*)regA;
  bf16* dt = (bf16*)regA;
  bf16* wbf_out = (bf16*)regA;
  bf16* xc_raw = (bf16*)regB;
  bf16* wbf_x = (bf16*)regB;
  bf16* wbf_dt = (bf16*)regB + 262144;
  bf16* yg = (bf16*)regB;

  // c1/c2) convert x and in_proj to bf16
  cvt_k<<<4096, 256, 0, stream>>>(x, xbf, TOK * DMODEL / 4);
  cvt_k<<<4096, 256, 0, stream>>>(in_proj, wbf_in, 2 * DI * DMODEL / 4);
  // d1) xc_raw = x @ in_proj[0:2048]^T
  gemm_nt<0><<<dim3(16, 32, 1), 256, 0, stream>>>(
      xbf, DMODEL, wbf_in, DMODEL, DI, DMODEL, DI, xc_raw, nullptr, nullptr);
  // d2) z = x @ in_proj[2048:4096]^T
  gemm_nt<0><<<dim3(16, 32, 1), 256, 0, stream>>>(
      xbf, DMODEL, wbf_in + (long)DI * DMODEL, DMODEL, DI, DMODEL, DI, z,
      nullptr, nullptr);
  // d3) causal conv + SiLU -> xcb
  conv_silu_k<<<(TOK * DI) / 256, 256, 0, stream>>>(xc_raw, conv_w, conv_b,
                                                    xcb);
  // c3/c4) convert x_proj, dt_proj
  cvt_k<<<192, 256, 0, stream>>>(x_proj, wbf_x, NX * DI / 4);
  cvt_k<<<128, 256, 0, stream>>>(dt_proj, wbf_dt, DI * DTR / 4);
  // d4) x_dbl partials (split-K over K=2048)
  gemm_nt<1><<<dim3(1, 32, KSPLIT), 256, 0, stream>>>(
      xcb, DI, wbf_x, DI, NX, DI / KSPLIT, 0, nullptr, part, nullptr);
  // d5) reduce partials -> xdbl f32, dtin bf16
  xdbl_reduce_k<<<(TOK * NX) / 256, 256, 0, stream>>>(part, xdbl, dtin);
  // d6) dt = softplus(dtin @ dt_proj^T + dt_b)  bf16
  gemm_nt<2><<<dim3(16, 32, 1), 256, 0, stream>>>(
      dtin, DTR, wbf_dt, DTR, DI, DTR, DI, dt, nullptr, dt_b);
  // s1) chunk summaries (P, S)
  scan_p1<<<dim3(DI / 256, NCH, 2), 256, 0, stream>>>(dt, xcb, xdbl, A_log, PH,
                                                      S);
  // s2) serial prefix over chunks -> Hin (in place over PH)
  scan_comb<<<(2 * DI * DSTATE) / 256, 256, 0, stream>>>(PH, S);
  // s3) replay with Hin, emit gated y -> yg
  scan_p2<<<dim3(DI / 256, NCH, 2), 256, 0, stream>>>(dt, xcb, xdbl, z, A_log,
                                                      Dp, PH, yg);
  // c5) convert out_proj
  cvt_k<<<2048, 256, 0, stream>>>(out_proj, wbf_out, DMODEL * DI / 4);
  // d8) out = yg @ out_proj^T -> f32 d_out
  gemm_nt<3><<<dim3(8, 32, 1), 256, 0, stream>>>(
      yg, DI, wbf_out, DI, DMODEL, DI, DMODEL, nullptr, (float*)d_out,
      nullptr);
}